// Round 6
// baseline (345.550 us; speedup 1.0000x reference)
//
#include <hip/hip_runtime.h>
#include <hip/hip_bf16.h>

typedef __attribute__((ext_vector_type(4))) float floatx4;
typedef __attribute__((ext_vector_type(8))) short shortx8;

#define NB   16
#define CIN  256
#define COUT 256
#define KW   3
#define LL   4096
#define LLP  4098   // LL + 2 guard rows (zeros) per b in xt
#define NR   5
#define QK   768    // CIN*KW
#define NP   65536  // NB*LL

static __device__ __forceinline__ unsigned short bf16bits(float f) {
    __hip_bfloat16 h = __float2bfloat16(f);
    return __builtin_bit_cast(unsigned short, h);
}

// async global->LDS, 16B per lane, LDS dest = wave-uniform base + lane*16
static __device__ __forceinline__ void gload16(const void* g, void* l) {
    __builtin_amdgcn_global_load_lds(
        (const __attribute__((address_space(1))) void*)g,
        (__attribute__((address_space(3))) void*)l, 16, 0, 0);
}

// ---------------- K0b: weights -> bf16 + zero xt guard rows ----------------
__global__ void k_wprep(const float* __restrict__ bk, __hip_bfloat16* __restrict__ wb,
                        __hip_bfloat16* __restrict__ xt) {
    int i = blockIdx.x * 256 + threadIdx.x;
    if (i < NB * 2 * CIN) {   // guard rows 0,1 of each b-slab = causal zeros
        int bb = i >> 9, rr = i & 511;
        xt[(size_t)bb * LLP * CIN + rr] = __float2bfloat16(0.f);
    }
    if (i >= NR * COUT * QK) return;
    int m = i / QK, q = i % QK;
    int o = (m / 80) * 16 + (m & 15);
    int r = (m % 80) / 16;
    int k = q >> 8, cin = q & 255;
    wb[i] = __float2bfloat16(bk[((r * COUT + o) * CIN + cin) * KW + k]);
}

// ---------------- K1: fused transpose + controller + softmax (no atomics) ----------------
// One block per (64-position tile, batch). Loops the 4 x 64-cin chunks: transpose-write
// xt chunk + accumulate controller logits. Softmax in-block -> fr written once.
__global__ void k_tfr(const float* __restrict__ x, const float* __restrict__ cw,
                      const float* __restrict__ cb,
                      __hip_bfloat16* __restrict__ xt, float* __restrict__ fr) {
    __shared__ float t[66][65];        // row = l_local+2 (halo rows 0,1), col = cin-in-chunk
    __shared__ float cwsh[QK * NR];    // full controller weights, 15360 B
    int l0 = blockIdx.x * 64, b = blockIdx.y;
    int tid = threadIdx.x;
    int r16 = tid >> 4, q16 = tid & 15;
    int p = tid >> 2, q = tid & 3;

    for (int i = tid; i < QK * NR; i += 256) cwsh[i] = cw[i];

    float lg[NR] = {0.f, 0.f, 0.f, 0.f, 0.f};
    for (int ch = 0; ch < 4; ++ch) {
        __syncthreads();   // protect t reuse (and cwsh on first iter)
        #pragma unroll
        for (int pass = 0; pass < 4; ++pass) {
            int cin = pass * 16 + r16;
            float4 v = *(const float4*)&x[((size_t)(b * CIN + ch * 64 + cin)) * LL + l0 + q16 * 4];
            t[q16 * 4 + 2][cin] = v.x;
            t[q16 * 4 + 3][cin] = v.y;
            t[q16 * 4 + 4][cin] = v.z;
            t[q16 * 4 + 5][cin] = v.w;
        }
        if (tid < 128) {  // halo cols l0-2, l0-1 (zeros at l0==0: causal pad)
            int cin = tid >> 1, j = tid & 1;
            float v = 0.f;
            if (l0 > 0) v = x[((size_t)(b * CIN + ch * 64 + cin)) * LL + l0 - 2 + j];
            t[j][cin] = v;
        }
        __syncthreads();

        // transpose write: xt[b, 2+l, ch*64+cin] bf16 (guard-row layout)
        #pragma unroll
        for (int pass = 0; pass < 4; ++pass) {
            int lr = pass * 16 + r16;
            int c4 = q16 * 4;
            ushort4 u;
            u.x = bf16bits(t[lr + 2][c4 + 0]);
            u.y = bf16bits(t[lr + 2][c4 + 1]);
            u.z = bf16bits(t[lr + 2][c4 + 2]);
            u.w = bf16bits(t[lr + 2][c4 + 3]);
            *(ushort4*)&xt[((size_t)(b * LLP + 2 + l0 + lr)) * CIN + ch * 64 + c4] = u;
        }

        // controller partials: 4 threads per position, 16 cins each
        #pragma unroll 4
        for (int ci = 0; ci < 16; ++ci) {
            int cin = q * 16 + ci;
            float x0 = t[p][cin], x1 = t[p + 1][cin], x2 = t[p + 2][cin];
            const float* w = &cwsh[(ch * 64 + cin) * 3 * NR];
            #pragma unroll
            for (int n = 0; n < NR; ++n)
                lg[n] += x0 * w[n] + x1 * w[NR + n] + x2 * w[2 * NR + n];
        }
    }
    #pragma unroll
    for (int n = 0; n < NR; ++n) {
        lg[n] += __shfl_xor(lg[n], 1);
        lg[n] += __shfl_xor(lg[n], 2);
    }
    if (q == 0) {
        float l2[NR];
        #pragma unroll
        for (int n = 0; n < NR; ++n) l2[n] = lg[n] + cb[n];
        float m = l2[0];
        #pragma unroll
        for (int n = 1; n < NR; ++n) m = fmaxf(m, l2[n]);
        float e[NR], s = 0.f;
        #pragma unroll
        for (int n = 0; n < NR; ++n) { e[n] = __expf(l2[n] - m); s += e[n]; }
        float inv = 1.f / s;
        #pragma unroll
        for (int n = 0; n < NR; ++n) fr[(size_t)(b * LL + l0 + p) * NR + n] = e[n] * inv;
    }
}

// ---------------- K2: conv + mixture; W in LDS, X (B-operand) direct from L2 ----------------
// GEMM M=1280, N=65536, K=768. Block 256 thr / 4 waves, tile M=80 x N=256, wave 80x64.
// 4 K-phases of 64 cins. LDS holds ONLY W: per phase 240 strips x 64 cins = 30 KB,
// double-buffered (61.4 KB -> 2 blocks/CU). B-fragments are loaded per-lane straight
// from xt (guard-row layout, L2-resident for the 16 y-blocks sharing this pt).
// This moves the 3x kh re-read redundancy off the saturated LDS port onto idle L2:
// LDS traffic/block drops 1.14 MB -> 0.60 MB (A-reads 480 KB + W-writes 120 KB).
// W strip = 128 B (8 chunks): A-read swizzle phys = (quad+4*csi) ^ (l16&7) spreads the
// 16 strip-rows over all 8 chunk-slots (2 lanes/slot = conflict-free b128).
#define WCH   1920    // W chunks per phase (240 strips * 8)
#define WBUF  15360   // shorts per W buffer
__global__ __launch_bounds__(256, 2)
void k_conv(const __hip_bfloat16* __restrict__ xt, const __hip_bfloat16* __restrict__ wb,
            const float* __restrict__ fr, const float* __restrict__ bias,
            float* __restrict__ out) {
    __shared__ __align__(16) short Wl[2 * WBUF];   // 61440 B
    __shared__ float bs[80];                       // 320 B

    int g = blockIdx.x;
    int pt = ((g >> 7) << 3) | (g & 7);   // XCD swizzle: same pt -> same XCD (mod-8)
    int y  = (g >> 3) & 15;
    int p0 = pt * 256;
    int m0 = y * 80, o0 = y * 16;
    int b = p0 >> 12, l0 = p0 & (LL - 1);
    int tid = threadIdx.x;
    int lane = tid & 63, wn = tid >> 6;
    int quad = lane >> 4, l16 = lane & 15;

    const __hip_bfloat16* xb = xt + (size_t)b * (LLP * CIN);

    if (tid < 80) bs[tid] = bias[(tid >> 4) * COUT + o0 + (tid & 15)];

    // ---- W staging source offsets (elements); phase adds 64 ----
    int wsrc[8];
    #pragma unroll
    for (int j = 0; j < 8; ++j) {
        int i = j * 256 + tid;
        if (i < WCH) {
            int s = i >> 3, cs = i & 7;
            int cg = cs ^ (s & 7);             // pre-swizzled source octet
            int kh = s / 80, m = s - kh * 80;
            wsrc[j] = (m0 + m) * QK + kh * 256 + cg * 8;
        } else wsrc[j] = 0;
    }

    // ---- B-operand per-lane global row bases (guard layout: data row l at idx l+2,
    //      and col p with tap kh reads data row p+kh-2 -> xt idx p+kh) ----
    const __hip_bfloat16* bbase[4];
    #pragma unroll
    for (int nf = 0; nf < 4; ++nf)
        bbase[nf] = xb + (size_t)(l0 + wn * 64 + nf * 16 + l16) * CIN + quad * 8;

    // ---- A (W) LDS read bases: aoff(kh,mf,csi) = (kh*80+mf*16+l16)*64 + phys*8,
    //      phys = (quad+4*csi) ^ (l16&7)  (note (kh*80+mf*16+l16)&7 == l16&7) ----
    int abase0 = l16 * 64 + ((quad    ) ^ (l16 & 7)) * 8;
    int abase1 = l16 * 64 + ((quad + 4) ^ (l16 & 7)) * 8;

    floatx4 acc[NR][4];
    #pragma unroll
    for (int mf = 0; mf < NR; ++mf)
        #pragma unroll
        for (int nf = 0; nf < 4; ++nf)
            acc[mf][nf] = (floatx4){0.f, 0.f, 0.f, 0.f};

    auto stageW = [&](int buf, int ph) {
        short* B = &Wl[buf * WBUF];
        const __hip_bfloat16* wp = wb + ph * 64;
        #pragma unroll
        for (int j = 0; j < 8; ++j) {
            int i = j * 256 + tid;
            if (j < 7 || i < WCH)
                gload16(wp + wsrc[j], B + i * 8);
        }
    };

    auto compute = [&](int buf, int ph) {
        const short* W = &Wl[buf * WBUF];
        #pragma unroll
        for (int kh = 0; kh < 3; ++kh) {
            #pragma unroll
            for (int csi = 0; csi < 2; ++csi) {
                shortx8 bfrag[4], afrag[NR];
                #pragma unroll
                for (int nf = 0; nf < 4; ++nf)
                    bfrag[nf] = *(const shortx8*)(bbase[nf] + kh * CIN + ph * 64 + csi * 32);
                int ab = csi ? abase1 : abase0;
                #pragma unroll
                for (int mf = 0; mf < NR; ++mf)
                    afrag[mf] = *(const shortx8*)&W[(kh * 80 + mf * 16) * 64 + ab];
                #pragma unroll
                for (int mf = 0; mf < NR; ++mf)
                    #pragma unroll
                    for (int nf = 0; nf < 4; ++nf)
                        acc[mf][nf] = __builtin_amdgcn_mfma_f32_16x16x32_bf16(
                            afrag[mf], bfrag[nf], acc[mf][nf], 0, 0, 0);
            }
        }
    };

    // ---- round-2-proven schedule: stage(ph+1) in flight over compute(ph), drain at sync ----
    stageW(0, 0);
    __syncthreads();
    #pragma unroll
    for (int ph = 0; ph < 4; ++ph) {
        if (ph < 3) stageW((ph + 1) & 1, ph + 1);
        compute(ph & 1, ph);
        __syncthreads();
    }

    // ---- epilogue: out[b, o0+olo, l0+colp] = sum_r fr[p][r]*(acc[r] + bias[r][o]) ----
    #pragma unroll
    for (int nf = 0; nf < 4; ++nf) {
        int colp = wn * 64 + nf * 16 + l16;
        const float* fp = fr + (size_t)(p0 + colp) * NR;
        float f0 = fp[0], f1 = fp[1], f2 = fp[2], f3 = fp[3], f4 = fp[4];
        #pragma unroll
        for (int j = 0; j < 4; ++j) {
            int olo = quad * 4 + j;
            float v = f0 * (acc[0][nf][j] + bs[0 * 16 + olo])
                    + f1 * (acc[1][nf][j] + bs[1 * 16 + olo])
                    + f2 * (acc[2][nf][j] + bs[2 * 16 + olo])
                    + f3 * (acc[3][nf][j] + bs[3 * 16 + olo])
                    + f4 * (acc[4][nf][j] + bs[4 * 16 + olo]);
            out[((size_t)(b * COUT + o0 + olo)) * LL + l0 + colp] = v;
        }
    }
}

extern "C" void kernel_launch(void* const* d_in, const int* in_sizes, int n_in,
                              void* d_out, int out_size, void* d_ws, size_t ws_size,
                              hipStream_t stream) {
    const float* x  = (const float*)d_in[0];
    const float* bk = (const float*)d_in[1];
    const float* bb = (const float*)d_in[2];
    const float* cw = (const float*)d_in[3];
    const float* cb = (const float*)d_in[4];
    float* out = (float*)d_out;

    char* ws = (char*)d_ws;
    __hip_bfloat16* xt = (__hip_bfloat16*)ws;                          // 16*4098*256*2 = 33,570,816 B
    __hip_bfloat16* wb = (__hip_bfloat16*)(ws + 33570816);             //  1,966,080 B
    float*          fr = (float*)(ws + 33570816 + 1966080);            //  1,310,720 B

    k_wprep<<<dim3((NR * COUT * QK + 255) / 256), dim3(256), 0, stream>>>(bk, wb, xt);
    k_tfr<<<dim3(LL / 64, NB), dim3(256), 0, stream>>>(x, cw, cb, xt, fr);
    k_conv<<<dim3(NP / 256 * (COUT / 16)), dim3(256), 0, stream>>>(xt, wb, fr, bb, out);
}

// Round 7
// 259.916 us; speedup vs baseline: 1.3295x; 1.3295x over previous
//
#include <hip/hip_runtime.h>
#include <hip/hip_bf16.h>

typedef __attribute__((ext_vector_type(4))) float floatx4;
typedef __attribute__((ext_vector_type(8))) short shortx8;

#define NB   16
#define CIN  256
#define COUT 256
#define KW   3
#define LL   4096
#define LLP  4098   // LL + 2 guard rows (zeros) per b in xt
#define NR   5
#define QK   768    // CIN*KW
#define NP   65536  // NB*LL

static __device__ __forceinline__ unsigned short bf16bits(float f) {
    __hip_bfloat16 h = __float2bfloat16(f);
    return __builtin_bit_cast(unsigned short, h);
}

// async global->LDS, 16B per lane, LDS dest = wave-uniform base + lane*16
static __device__ __forceinline__ void gload16(const void* g, void* l) {
    __builtin_amdgcn_global_load_lds(
        (const __attribute__((address_space(1))) void*)g,
        (__attribute__((address_space(3))) void*)l, 16, 0, 0);
}

// ---------------- K1: fused wprep + transpose + controller + softmax ----------------
// Also performs (a) weight prep into wb (M-order), (b) xt guard-row zeroing.
__global__ void k_tfr(const float* __restrict__ x, const float* __restrict__ cw,
                      const float* __restrict__ cb, const float* __restrict__ bk,
                      __hip_bfloat16* __restrict__ wb,
                      __hip_bfloat16* __restrict__ xt, float* __restrict__ fr) {
    __shared__ float t[66][65];        // row = l_local+2 (halo rows 0,1), col = cin-in-chunk
    __shared__ float cwsh[QK * NR];    // full controller weights, 15360 B
    int l0 = blockIdx.x * 64, b = blockIdx.y;
    int bid = blockIdx.y * 64 + blockIdx.x;           // 0..1023
    int tid = threadIdx.x;
    int r16 = tid >> 4, q16 = tid & 15;
    int p = tid >> 2, q = tid & 3;

    // --- integrated wprep: wb[m*QK + k*256 + cin], m = (o>>4)*80 + r*16 + (o&15) ---
    #pragma unroll
    for (int jj = 0; jj < 4; ++jj) {
        int i = bid * 1024 + jj * 256 + tid;
        if (i < NR * COUT * QK) {
            int m = i / QK, qq = i % QK;
            int o = (m / 80) * 16 + (m & 15);
            int r = (m % 80) / 16;
            int k = qq >> 8, cin = qq & 255;
            wb[i] = __float2bfloat16(bk[((r * COUT + o) * CIN + cin) * KW + k]);
        }
    }
    {   // guard rows 0,1 of each b-slab = causal zeros (8192 elems)
        int i0 = bid * 256 + tid;
        if (i0 < NB * 2 * CIN) {
            int bb = i0 >> 9, rr = i0 & 511;
            xt[(size_t)bb * LLP * CIN + rr] = __float2bfloat16(0.f);
        }
    }

    for (int i = tid; i < QK * NR; i += 256) cwsh[i] = cw[i];

    float lg[NR] = {0.f, 0.f, 0.f, 0.f, 0.f};
    for (int ch = 0; ch < 4; ++ch) {
        __syncthreads();   // protect t reuse (and cwsh on first iter)
        #pragma unroll
        for (int pass = 0; pass < 4; ++pass) {
            int cin = pass * 16 + r16;
            float4 v = *(const float4*)&x[((size_t)(b * CIN + ch * 64 + cin)) * LL + l0 + q16 * 4];
            t[q16 * 4 + 2][cin] = v.x;
            t[q16 * 4 + 3][cin] = v.y;
            t[q16 * 4 + 4][cin] = v.z;
            t[q16 * 4 + 5][cin] = v.w;
        }
        if (tid < 128) {  // halo cols l0-2, l0-1 (zeros at l0==0: causal pad)
            int cin = tid >> 1, j = tid & 1;
            float v = 0.f;
            if (l0 > 0) v = x[((size_t)(b * CIN + ch * 64 + cin)) * LL + l0 - 2 + j];
            t[j][cin] = v;
        }
        __syncthreads();

        // transpose write: xt[b, 2+l, ch*64+cin] bf16 (guard-row layout)
        #pragma unroll
        for (int pass = 0; pass < 4; ++pass) {
            int lr = pass * 16 + r16;
            int c4 = q16 * 4;
            ushort4 u;
            u.x = bf16bits(t[lr + 2][c4 + 0]);
            u.y = bf16bits(t[lr + 2][c4 + 1]);
            u.z = bf16bits(t[lr + 2][c4 + 2]);
            u.w = bf16bits(t[lr + 2][c4 + 3]);
            *(ushort4*)&xt[((size_t)(b * LLP + 2 + l0 + lr)) * CIN + ch * 64 + c4] = u;
        }

        // controller partials: 4 threads per position, 16 cins each
        #pragma unroll 4
        for (int ci = 0; ci < 16; ++ci) {
            int cin = q * 16 + ci;
            float x0 = t[p][cin], x1 = t[p + 1][cin], x2 = t[p + 2][cin];
            const float* w = &cwsh[(ch * 64 + cin) * 3 * NR];
            #pragma unroll
            for (int n = 0; n < NR; ++n)
                lg[n] += x0 * w[n] + x1 * w[NR + n] + x2 * w[2 * NR + n];
        }
    }
    #pragma unroll
    for (int n = 0; n < NR; ++n) {
        lg[n] += __shfl_xor(lg[n], 1);
        lg[n] += __shfl_xor(lg[n], 2);
    }
    if (q == 0) {
        float l2[NR];
        #pragma unroll
        for (int n = 0; n < NR; ++n) l2[n] = lg[n] + cb[n];
        float m = l2[0];
        #pragma unroll
        for (int n = 1; n < NR; ++n) m = fmaxf(m, l2[n]);
        float e[NR], s = 0.f;
        #pragma unroll
        for (int n = 0; n < NR; ++n) { e[n] = __expf(l2[n] - m); s += e[n]; }
        float inv = 1.f / s;
        #pragma unroll
        for (int n = 0; n < NR; ++n) fr[(size_t)(b * LL + l0 + p) * NR + n] = e[n] * inv;
    }
}

// ---------------- K2: conv + mixture; X ring-of-3 + W ring-of-2, counted vmcnt (T3+T4+T5) ----------------
// GEMM M=1280, N=65536, K=768. Block 256 thr / 4 waves, tile M=80 x N=256, wave 80x64.
// 8 K-phases of 32 cins. X slab: 258 rows x 32 cins = 1032 chunks (16.5 KB), ring of 3
// (depth-2 prefetch). W slab: 240 strips x 32 cins = 960 chunks (15 KB), ring of 2
// (depth-1; W is L2-resident). LDS = 3*16512 + 2*15360 = 80,256 B -> 2 blocks/CU.
// Uniform staging: X = 5 calls/wave (5th overlaps chunks 968..1031, rewrite-same-data),
// W = 4 calls (4th overlaps 704..959). Steady wait = vmcnt(5): drains X(k)+W(k), leaves
// X(k+1) in flight across the barrier; vmcnt(0) only at the last phase.
// Guard-row layout: LDS X row r = xt row l0+r = data row l0+r-2 -> no halo special case.
// Swizzle f(row)=(row>>1)&3 on 64B rows: conflict-free ds_read_b128 (round-2/5 verified).
#define XBUF  8256    // shorts per X slab (1032 chunks)
#define WBUF  7680    // shorts per W slab (960 chunks)
#define WOFF  24768   // short offset of W region (3 * XBUF)
__global__ __launch_bounds__(256, 2)
void k_conv(const __hip_bfloat16* __restrict__ xt, const __hip_bfloat16* __restrict__ wb,
            const float* __restrict__ fr, const float* __restrict__ bias,
            float* __restrict__ out) {
    __shared__ __align__(16) short lds[3 * XBUF + 2 * WBUF];  // 80,256 B
    __shared__ float bs[80];                                  // 320 B

    int g = blockIdx.x;
    int pt = ((g >> 7) << 3) | (g & 7);   // XCD swizzle: g=128a+8y+x -> pt=8a+x (bijective)
    int y  = (g >> 3) & 15;
    int p0 = pt * 256;
    int m0 = y * 80, o0 = y * 16;
    int b = p0 >> 12, l0 = p0 & (LL - 1);
    int tid = threadIdx.x;
    int lane = tid & 63, wn = tid >> 6;
    int quad = lane >> 4, l16 = lane & 15;

    const __hip_bfloat16* xb = xt + (size_t)b * (LLP * CIN);

    if (tid < 80) bs[tid] = bias[(tid >> 4) * COUT + o0 + (tid & 15)];

    // ---- X staging: chunk c -> row c>>2, slot (c&3)^f(row); phase adds 32 elems ----
    int xchk[5];
    #pragma unroll
    for (int j = 0; j < 4; ++j) xchk[j] = j * 256 + tid;
    xchk[4] = 968 + lane;                  // overlap call: all waves rewrite 968..1031
    int xsrc[5];
    #pragma unroll
    for (int j = 0; j < 5; ++j) {
        int c = xchk[j];
        int row = c >> 2, cs = c & 3;
        int cg = cs ^ ((row >> 1) & 3);
        xsrc[j] = (l0 + row) * CIN + cg * 8;   // xt row l0+row = data row l0+row-2
    }
    // ---- W staging: chunk c -> strip c>>2 (= kh*80+m), slot (c&3)^g(strip) ----
    int wchk[4];
    #pragma unroll
    for (int j = 0; j < 3; ++j) wchk[j] = j * 256 + tid;
    wchk[3] = 704 + tid;                   // overlap call: rewrites 704..767
    int wsrc[4];
    #pragma unroll
    for (int j = 0; j < 4; ++j) {
        int c = wchk[j];
        int s = c >> 2, cs = c & 3;
        int cg = cs ^ ((s >> 1) & 3);
        int kh = s / 80, m = s - kh * 80;
        wsrc[j] = (m0 + m) * QK + kh * 256 + cg * 8;
    }

    // ---- LDS read offsets (shorts, within one slab) ----
    int boff[3][4], aoff[3][5];
    #pragma unroll
    for (int kh = 0; kh < 3; ++kh) {
        #pragma unroll
        for (int nf = 0; nf < 4; ++nf) {
            int row = wn * 64 + nf * 16 + l16 + kh;     // LDS row = colp + kh (0..257)
            boff[kh][nf] = row * 32 + (quad ^ ((row >> 1) & 3)) * 8;
        }
        #pragma unroll
        for (int mf = 0; mf < NR; ++mf) {
            int s = kh * 80 + mf * 16 + l16;
            aoff[kh][mf] = s * 32 + (quad ^ ((s >> 1) & 3)) * 8;
        }
    }

    floatx4 acc[NR][4];
    #pragma unroll
    for (int mf = 0; mf < NR; ++mf)
        #pragma unroll
        for (int nf = 0; nf < 4; ++nf)
            acc[mf][nf] = (floatx4){0.f, 0.f, 0.f, 0.f};

    auto stageX = [&](int buf, int ph) {   // exactly 5 gload16 per wave
        short* B = &lds[buf * XBUF];
        const __hip_bfloat16* xp = xb + ph * 32;
        #pragma unroll
        for (int j = 0; j < 5; ++j)
            gload16(xp + xsrc[j], B + xchk[j] * 8);
    };
    auto stageW = [&](int buf, int ph) {   // exactly 4 gload16 per wave
        short* B = &lds[WOFF + buf * WBUF];
        const __hip_bfloat16* wp = wb + ph * 32;
        #pragma unroll
        for (int j = 0; j < 4; ++j)
            gload16(wp + wsrc[j], B + wchk[j] * 8);
    };

    auto compute = [&](int ph) {
        const short* X = &lds[(ph % 3) * XBUF];
        const short* W = &lds[WOFF + (ph & 1) * WBUF];
        #pragma unroll
        for (int kh = 0; kh < 3; ++kh) {
            shortx8 bfrag[4], afrag[NR];
            #pragma unroll
            for (int nf = 0; nf < 4; ++nf)
                bfrag[nf] = *(const shortx8*)&X[boff[kh][nf]];
            #pragma unroll
            for (int mf = 0; mf < NR; ++mf)
                afrag[mf] = *(const shortx8*)&W[aoff[kh][mf]];
            #pragma unroll
            for (int mf = 0; mf < NR; ++mf)
                #pragma unroll
                for (int nf = 0; nf < 4; ++nf)
                    acc[mf][nf] = __builtin_amdgcn_mfma_f32_16x16x32_bf16(
                        afrag[mf], bfrag[nf], acc[mf][nf], 0, 0, 0);
        }
    };

    // ---- counted-vmcnt pipeline: X depth-2, W depth-1 ----
    stageW(0, 0); stageX(0, 0); stageX(1, 1);   // queue: W0(4), X0(5), X1(5)
    #pragma unroll
    for (int ph = 0; ph < 8; ++ph) {
        if (ph == 0)      asm volatile("s_waitcnt vmcnt(5) lgkmcnt(0)" ::: "memory");
        else if (ph < 7)  asm volatile("s_waitcnt vmcnt(5)" ::: "memory");   // X(ph)+W(ph) done
        else              asm volatile("s_waitcnt vmcnt(0)" ::: "memory");
        __builtin_amdgcn_s_barrier();          // slab ph ready in every wave
        __builtin_amdgcn_sched_barrier(0);     // pin: nothing hoists above the barrier
        if (ph < 7) stageW((ph + 1) & 1, ph + 1);   // overwrites W slab read at ph-1
        if (ph < 6) stageX((ph + 2) % 3, ph + 2);   // overwrites X slab read at ph-1
        __builtin_amdgcn_s_setprio(1);
        compute(ph);
        __builtin_amdgcn_s_setprio(0);
    }

    // ---- epilogue: out[b, o0+olo, l0+colp] = sum_r fr[p][r]*(acc[r] + bias[r][o]) ----
    #pragma unroll
    for (int nf = 0; nf < 4; ++nf) {
        int colp = wn * 64 + nf * 16 + l16;
        const float* fp = fr + (size_t)(p0 + colp) * NR;
        float f0 = fp[0], f1 = fp[1], f2 = fp[2], f3 = fp[3], f4 = fp[4];
        #pragma unroll
        for (int j = 0; j < 4; ++j) {
            int olo = quad * 4 + j;
            float v = f0 * (acc[0][nf][j] + bs[0 * 16 + olo])
                    + f1 * (acc[1][nf][j] + bs[1 * 16 + olo])
                    + f2 * (acc[2][nf][j] + bs[2 * 16 + olo])
                    + f3 * (acc[3][nf][j] + bs[3 * 16 + olo])
                    + f4 * (acc[4][nf][j] + bs[4 * 16 + olo]);
            out[((size_t)(b * COUT + o0 + olo)) * LL + l0 + colp] = v;
        }
    }
}

extern "C" void kernel_launch(void* const* d_in, const int* in_sizes, int n_in,
                              void* d_out, int out_size, void* d_ws, size_t ws_size,
                              hipStream_t stream) {
    const float* x  = (const float*)d_in[0];
    const float* bk = (const float*)d_in[1];
    const float* bb = (const float*)d_in[2];
    const float* cw = (const float*)d_in[3];
    const float* cb = (const float*)d_in[4];
    float* out = (float*)d_out;

    char* ws = (char*)d_ws;
    __hip_bfloat16* xt = (__hip_bfloat16*)ws;                          // 16*4098*256*2 = 33,570,816 B
    __hip_bfloat16* wb = (__hip_bfloat16*)(ws + 33570816);             //  1,966,080 B
    float*          fr = (float*)(ws + 33570816 + 1966080);            //  1,310,720 B

    k_tfr<<<dim3(LL / 64, NB), dim3(256), 0, stream>>>(x, cw, cb, bk, wb, xt, fr);
    k_conv<<<dim3(NP / 256 * (COUT / 16)), dim3(256), 0, stream>>>(xt, wb, fr, bb, out);
}

// Round 8
// 253.950 us; speedup vs baseline: 1.3607x; 1.0235x over previous
//
#include <hip/hip_runtime.h>
#include <hip/hip_bf16.h>

typedef __attribute__((ext_vector_type(4))) float floatx4;
typedef __attribute__((ext_vector_type(8))) short shortx8;

#define NB   16
#define CIN  256
#define COUT 256
#define KW   3
#define LL   4096
#define LLP  4098   // LL + 2 guard rows (zeros) per b in xt
#define NR   5
#define QK   768    // CIN*KW
#define NP   65536  // NB*LL

static __device__ __forceinline__ unsigned short bf16bits(float f) {
    __hip_bfloat16 h = __float2bfloat16(f);
    return __builtin_bit_cast(unsigned short, h);
}

// async global->LDS, 16B per lane, LDS dest = wave-uniform base + lane*16
static __device__ __forceinline__ void gload16(const void* g, void* l) {
    __builtin_amdgcn_global_load_lds(
        (const __attribute__((address_space(1))) void*)g,
        (__attribute__((address_space(3))) void*)l, 16, 0, 0);
}

// ---------------- K1: transpose + weight prep (wb, wc) + guard-row zeroing ----------------
// Controller math moved into k_conv; this is now a pure data-movement kernel.
// wc layout: [kh*16 + r][cin] bf16, r<5 -> cw[(cin*3+kh)*5 + r], r>=5 -> 0 (pad rows).
__global__ void k_tfr(const float* __restrict__ x, const float* __restrict__ bk,
                      const float* __restrict__ cw,
                      __hip_bfloat16* __restrict__ wb, __hip_bfloat16* __restrict__ wc,
                      __hip_bfloat16* __restrict__ xt) {
    __shared__ float t[64][65];
    int l0 = blockIdx.x * 64, b = blockIdx.y;
    int bid = blockIdx.y * 64 + blockIdx.x;           // 0..1023
    int tid = threadIdx.x;
    int r16 = tid >> 4, q16 = tid & 15;

    // --- wprep: wb[m*QK + k*256 + cin], m = (o>>4)*80 + r*16 + (o&15) ---
    #pragma unroll
    for (int jj = 0; jj < 4; ++jj) {
        int i = bid * 1024 + jj * 256 + tid;
        if (i < NR * COUT * QK) {
            int m = i / QK, qq = i % QK;
            int o = (m / 80) * 16 + (m & 15);
            int r = (m % 80) / 16;
            int k = qq >> 8, cin = qq & 255;
            wb[i] = __float2bfloat16(bk[((r * COUT + o) * CIN + cin) * KW + k]);
        }
    }
    // --- wc prep: 48 rows x 256 cins (blocks 0..47, one element/thread) ---
    if (bid < 48) {
        int row = bid, cin = tid;
        int kh = row >> 4, r = row & 15;
        float v = (r < NR) ? cw[(cin * 3 + kh) * NR + r] : 0.f;
        wc[row * 256 + cin] = __float2bfloat16(v);
    }
    // --- guard rows 0,1 of each b-slab = causal zeros (8192 elems) ---
    {
        int i0 = bid * 256 + tid;
        if (i0 < NB * 2 * CIN) {
            int bb = i0 >> 9, rr = i0 & 511;
            xt[(size_t)bb * LLP * CIN + rr] = __float2bfloat16(0.f);
        }
    }

    // --- transpose x (B,Cin,L) fp32 -> xt (B, 2+L, Cin) bf16 ---
    for (int ch = 0; ch < 4; ++ch) {
        __syncthreads();
        #pragma unroll
        for (int pass = 0; pass < 4; ++pass) {
            int cin = pass * 16 + r16;
            float4 v = *(const float4*)&x[((size_t)(b * CIN + ch * 64 + cin)) * LL + l0 + q16 * 4];
            t[q16 * 4 + 0][cin] = v.x;
            t[q16 * 4 + 1][cin] = v.y;
            t[q16 * 4 + 2][cin] = v.z;
            t[q16 * 4 + 3][cin] = v.w;
        }
        __syncthreads();
        #pragma unroll
        for (int pass = 0; pass < 4; ++pass) {
            int lr = pass * 16 + r16;
            int c4 = q16 * 4;
            ushort4 u;
            u.x = bf16bits(t[lr][c4 + 0]);
            u.y = bf16bits(t[lr][c4 + 1]);
            u.z = bf16bits(t[lr][c4 + 2]);
            u.w = bf16bits(t[lr][c4 + 3]);
            *(ushort4*)&xt[((size_t)(b * LLP + 2 + l0 + lr)) * CIN + ch * 64 + c4] = u;
        }
    }
}

// ---------------- K2: conv + controller + softmax + mixture, all in one GEMM ----------------
// GEMM M=1280(+ctrl), N=65536, K=768. Block 256 thr / 4 waves, wave tile 96x64:
// M-frags 0..4 = conv rows (80), frag 5 = controller rules (5 real + 11 zero-pad rows).
// Controller reuses the staged X (bfrag) for free -> logits accumulate in acc[5][*];
// epilogue does softmax in-block (per-wave LDS shuffle, stride-9 conflict-free) and
// the mixture, deleting k_tfr's controller pass and the fr buffer entirely.
// 8 K-phases of 32 cins. LDS: X dbuf 2x16.5 KB + W' (288 strips = 240 W + 48 ctrl)
// dbuf 2x18.4 KB = 69.9 KB -> 2 blocks/CU. Round-2-proven drain schedule
// (counted-vmcnt measured +1% only, r7). Swizzle f(s)=(s>>1)&3 (r2/r7 verified).
#define XBUF  8256    // shorts per X slab (1032 chunks)
#define WBUF2 9216    // shorts per W' slab (1152 chunks = 288 strips x 4)
#define WOFF2 16512   // short offset of W' region (2 * XBUF)
__global__ __launch_bounds__(256, 2)
void k_conv(const __hip_bfloat16* __restrict__ xt, const __hip_bfloat16* __restrict__ wb,
            const __hip_bfloat16* __restrict__ wc, const float* __restrict__ bias,
            const float* __restrict__ cbv, float* __restrict__ out) {
    __shared__ __align__(16) short lds[2 * XBUF + 2 * WBUF2];  // 69,888 B
    __shared__ float bs[80];                                   // 320 B

    int g = blockIdx.x;
    int pt = ((g >> 7) << 3) | (g & 7);   // XCD swizzle: g=128a+8y+x -> pt=8a+x (bijective)
    int y  = (g >> 3) & 15;
    int p0 = pt * 256;
    int m0 = y * 80, o0 = y * 16;
    int b = p0 >> 12, l0 = p0 & (LL - 1);
    int tid = threadIdx.x;
    int lane = tid & 63, wn = tid >> 6;
    int quad = lane >> 4, l16 = lane & 15;

    const __hip_bfloat16* xb = xt + (size_t)b * (LLP * CIN);

    if (tid < 80) bs[tid] = bias[(tid >> 4) * COUT + o0 + (tid & 15)];
    float cbl[NR];
    #pragma unroll
    for (int n = 0; n < NR; ++n) cbl[n] = cbv[n];

    // ---- X staging: chunk c -> row c>>2, slot (c&3)^f(row); phase adds 32 elems ----
    int xchk[5];
    #pragma unroll
    for (int j = 0; j < 4; ++j) xchk[j] = j * 256 + tid;
    xchk[4] = 968 + lane;                  // overlap call: all waves rewrite 968..1031
    int xsrc[5];
    #pragma unroll
    for (int j = 0; j < 5; ++j) {
        int c = xchk[j];
        int row = c >> 2, cs = c & 3;
        int cg = cs ^ ((row >> 1) & 3);
        xsrc[j] = (l0 + row) * CIN + cg * 8;   // xt row l0+row = data row l0+row-2
    }
    // ---- W' staging: 1152 chunks; strip s = c>>2 = kh*96 + m'; m'<80 -> wb, else wc ----
    int wchk[5];
    #pragma unroll
    for (int j = 0; j < 4; ++j) wchk[j] = j * 256 + tid;
    wchk[4] = 1024 + (tid & 127);          // overlap call: rewrites 1024..1151 twice
    const __hip_bfloat16* wp[5];
    #pragma unroll
    for (int j = 0; j < 5; ++j) {
        int c = wchk[j];
        int s = c >> 2, cs = c & 3;
        int cg = cs ^ ((s >> 1) & 3);
        int kh = s / 96, mp = s - kh * 96;
        wp[j] = (mp < 80) ? wb + ((m0 + mp) * QK + kh * 256 + cg * 8)
                          : wc + ((kh * 16 + mp - 80) * 256 + cg * 8);
    }

    // ---- LDS read offsets (shorts, within one slab) ----
    int boff[3][4], aoff[3][6];
    #pragma unroll
    for (int kh = 0; kh < 3; ++kh) {
        #pragma unroll
        for (int nf = 0; nf < 4; ++nf) {
            int row = wn * 64 + nf * 16 + l16 + kh;     // LDS row = colp + kh (0..257)
            boff[kh][nf] = row * 32 + (quad ^ ((row >> 1) & 3)) * 8;
        }
        #pragma unroll
        for (int mf = 0; mf < 6; ++mf) {
            int s = kh * 96 + mf * 16 + l16;
            aoff[kh][mf] = s * 32 + (quad ^ ((s >> 1) & 3)) * 8;
        }
    }

    floatx4 acc[6][4];
    #pragma unroll
    for (int mf = 0; mf < 6; ++mf)
        #pragma unroll
        for (int nf = 0; nf < 4; ++nf)
            acc[mf][nf] = (floatx4){0.f, 0.f, 0.f, 0.f};

    auto stage = [&](int buf, int ph) {     // exactly 10 gload16 per wave
        short* BX = &lds[buf * XBUF];
        const __hip_bfloat16* xp = xb + ph * 32;
        #pragma unroll
        for (int j = 0; j < 5; ++j)
            gload16(xp + xsrc[j], BX + xchk[j] * 8);
        short* BW = &lds[WOFF2 + buf * WBUF2];
        #pragma unroll
        for (int j = 0; j < 5; ++j)
            gload16(wp[j] + ph * 32, BW + wchk[j] * 8);
    };

    auto compute = [&](int buf) {
        const short* X = &lds[buf * XBUF];
        const short* W = &lds[WOFF2 + buf * WBUF2];
        #pragma unroll
        for (int kh = 0; kh < 3; ++kh) {
            shortx8 bfrag[4], afrag[6];
            #pragma unroll
            for (int nf = 0; nf < 4; ++nf)
                bfrag[nf] = *(const shortx8*)&X[boff[kh][nf]];
            #pragma unroll
            for (int mf = 0; mf < 6; ++mf)
                afrag[mf] = *(const shortx8*)&W[aoff[kh][mf]];
            #pragma unroll
            for (int mf = 0; mf < 6; ++mf)
                #pragma unroll
                for (int nf = 0; nf < 4; ++nf)
                    acc[mf][nf] = __builtin_amdgcn_mfma_f32_16x16x32_bf16(
                        afrag[mf], bfrag[nf], acc[mf][nf], 0, 0, 0);
        }
    };

    // ---- round-2-proven drain schedule ----
    stage(0, 0);
    __syncthreads();
    #pragma unroll
    for (int ph = 0; ph < 8; ++ph) {
        if (ph < 7) stage((ph + 1) & 1, ph + 1);
        compute(ph & 1);
        __syncthreads();
    }

    // ---- epilogue 1: publish controller logits (acc[5]) per position via LDS ----
    // sc[pos_in_wave][9] floats per wave (stride 9 -> conflict-free); rules live in
    // quad0 regs j=0..3 (rows 0-3) and quad1 reg j=0 (row 4).
    float* scf = (float*)lds;
    int pb = wn * 576;   // 64 * 9
    #pragma unroll
    for (int nf = 0; nf < 4; ++nf) {
        int pp = pb + (nf * 16 + l16) * 9;
        if (quad == 0) {
            scf[pp + 0] = acc[5][nf][0];
            scf[pp + 1] = acc[5][nf][1];
            scf[pp + 2] = acc[5][nf][2];
            scf[pp + 3] = acc[5][nf][3];
        } else if (quad == 1) {
            scf[pp + 4] = acc[5][nf][0];
        }
    }
    __syncthreads();

    // ---- epilogue 2: softmax + mixture + store ----
    #pragma unroll
    for (int nf = 0; nf < 4; ++nf) {
        int colp = wn * 64 + nf * 16 + l16;
        int pp = pb + (nf * 16 + l16) * 9;
        float l2[NR];
        #pragma unroll
        for (int n = 0; n < NR; ++n) l2[n] = scf[pp + n] + cbl[n];
        float mx = l2[0];
        #pragma unroll
        for (int n = 1; n < NR; ++n) mx = fmaxf(mx, l2[n]);
        float e[NR], s = 0.f;
        #pragma unroll
        for (int n = 0; n < NR; ++n) { e[n] = __expf(l2[n] - mx); s += e[n]; }
        float inv = 1.f / s;
        float f0 = e[0] * inv, f1 = e[1] * inv, f2 = e[2] * inv, f3 = e[3] * inv, f4 = e[4] * inv;
        #pragma unroll
        for (int j = 0; j < 4; ++j) {
            int olo = quad * 4 + j;
            float v = f0 * (acc[0][nf][j] + bs[0 * 16 + olo])
                    + f1 * (acc[1][nf][j] + bs[1 * 16 + olo])
                    + f2 * (acc[2][nf][j] + bs[2 * 16 + olo])
                    + f3 * (acc[3][nf][j] + bs[3 * 16 + olo])
                    + f4 * (acc[4][nf][j] + bs[4 * 16 + olo]);
            out[((size_t)(b * COUT + o0 + olo)) * LL + l0 + colp] = v;
        }
    }
}

extern "C" void kernel_launch(void* const* d_in, const int* in_sizes, int n_in,
                              void* d_out, int out_size, void* d_ws, size_t ws_size,
                              hipStream_t stream) {
    const float* x  = (const float*)d_in[0];
    const float* bk = (const float*)d_in[1];
    const float* bb = (const float*)d_in[2];
    const float* cw = (const float*)d_in[3];
    const float* cb = (const float*)d_in[4];
    float* out = (float*)d_out;

    char* ws = (char*)d_ws;
    __hip_bfloat16* xt = (__hip_bfloat16*)ws;                          // 16*4098*256*2 = 33,570,816 B
    __hip_bfloat16* wb = (__hip_bfloat16*)(ws + 33570816);             //  1,966,080 B
    __hip_bfloat16* wc = (__hip_bfloat16*)(ws + 33570816 + 1966080);   //     24,576 B

    k_tfr<<<dim3(LL / 64, NB), dim3(256), 0, stream>>>(x, bk, cw, wb, wc, xt);
    k_conv<<<dim3(NP / 256 * (COUT / 16)), dim3(256), 0, stream>>>(xt, wb, wc, bb, cb, out);
}